// Round 1
// baseline (12924.152 us; speedup 1.0000x reference)
//
#include <hip/hip_runtime.h>
#include <hip/hip_cooperative_groups.h>

namespace cg = cooperative_groups;

static constexpr int BATCH = 1024;
static constexpr int NIN   = 512;    // in_features
static constexpr int MOUT  = 1024;   // out_features
static constexpr float LAMBD = 0.2f;
static constexpr float TOLF  = 1e-4f;
static constexpr int MAX_ITERS = 100;
static constexpr int MM = BATCH * MOUT;   // 1M elements

// ---------------------------------------------------------------------------
// zero-init: v, u, encoded output, solved flags + counter
// ---------------------------------------------------------------------------
__global__ __launch_bounds__(256) void zero_init(float* v, float* u, float* enc,
                                                 int* solved) {
    int i = blockIdx.x * 256 + threadIdx.x;
    if (i < MM) { v[i] = 0.f; u[i] = 0.f; enc[i] = 0.f; }
    if (i <= BATCH) solved[i] = 0;   // solved[0..1023] flags, solved[1024] = count
}

// ---------------------------------------------------------------------------
// adb = x @ w^T   (1024x512 * (1024x512)^T -> 1024x1024), also beff = adb
// 64x64 tiles, BK=16, 4x4 per thread
// ---------------------------------------------------------------------------
__global__ __launch_bounds__(256) void gemm_adb(const float* __restrict__ x,
                                                const float* __restrict__ w,
                                                float* __restrict__ adb,
                                                float* __restrict__ beff) {
    __shared__ float As[16][72];
    __shared__ float Bs[16][72];
    const int tid = threadIdx.x;
    const int i0 = (blockIdx.x >> 4) * 64, j0 = (blockIdx.x & 15) * 64;
    const int tx = tid & 15, ty = tid >> 4;
    const int lr = tid >> 2, lk = (tid & 3) << 2;
    float acc[4][4] = {};
    for (int k0 = 0; k0 < NIN; k0 += 16) {
        float4 a4 = *(const float4*)&x[(i0 + lr) * NIN + k0 + lk];
        As[lk + 0][lr] = a4.x; As[lk + 1][lr] = a4.y;
        As[lk + 2][lr] = a4.z; As[lk + 3][lr] = a4.w;
        float4 b4 = *(const float4*)&w[(j0 + lr) * NIN + k0 + lk];  // w[j][k]
        Bs[lk + 0][lr] = b4.x; Bs[lk + 1][lr] = b4.y;
        Bs[lk + 2][lr] = b4.z; Bs[lk + 3][lr] = b4.w;
        __syncthreads();
        #pragma unroll
        for (int kk = 0; kk < 16; ++kk) {
            float a_[4], b_[4];
            #pragma unroll
            for (int r = 0; r < 4; ++r) a_[r] = As[kk][(ty << 2) + r];
            #pragma unroll
            for (int c = 0; c < 4; ++c) b_[c] = Bs[kk][(tx << 2) + c];
            #pragma unroll
            for (int r = 0; r < 4; ++r)
                #pragma unroll
                for (int c = 0; c < 4; ++c)
                    acc[r][c] = fmaf(a_[r], b_[c], acc[r][c]);
        }
        __syncthreads();
    }
    #pragma unroll
    for (int r = 0; r < 4; ++r) {
        float4 o = make_float4(acc[r][0], acc[r][1], acc[r][2], acc[r][3]);
        int idx = (i0 + (ty << 2) + r) * MOUT + j0 + (tx << 2);
        *(float4*)&adb[idx]  = o;
        *(float4*)&beff[idx] = o;
    }
}

// ---------------------------------------------------------------------------
// Cooperative ADMM kernel: 256 blocks x 256 threads (1 per CU).
// Per iteration:
//   phase A: xk = beff @ M_inv (each block: one 64x64 tile, K=1024)
//   grid.sync
//   phase B: each block updates 4 rows (one per wave): softshrink, norms,
//            convergence, freeze, write v_sol
//   grid.sync; global break when all rows solved
// ---------------------------------------------------------------------------
__global__ __launch_bounds__(256, 1)
void admm_kernel(const float* __restrict__ adb, float* beff, float* v, float* u,
                 float* __restrict__ xk, const float* __restrict__ Minv,
                 float* enc, int* solved, int* cnt) {
    cg::grid_group grid = cg::this_grid();
    __shared__ float As[16][72];
    __shared__ float Bs[16][72];

    const int tid = threadIdx.x;
    const int bx  = blockIdx.x;
    const int i0 = (bx >> 4) * 64, j0 = (bx & 15) * 64;
    const int tx = tid & 15, ty = tid >> 4;
    const int la_r = tid >> 2, la_k = (tid & 3) << 2;   // A tile load (transpose)
    const int lb_k = tid >> 4, lb_j = (tid & 15) << 2;  // B tile load (direct)
    const int lane = tid & 63;
    const int wrow = (bx << 2) + (tid >> 6);            // phase-B row for this wave

    for (int iter = 0; iter < MAX_ITERS; ++iter) {
        // ---- phase A: GEMM tile, skipped if all 64 rows of tile are solved
        bool rowDone = ((volatile const int*)solved)[i0 + lane] != 0;
        bool skip = (__ballot(rowDone) == 0xFFFFFFFFFFFFFFFFull);
        if (!skip) {
            float acc[4][4] = {};
            for (int k0 = 0; k0 < MOUT; k0 += 16) {
                float4 a4 = *(const float4*)&beff[(i0 + la_r) * MOUT + k0 + la_k];
                As[la_k + 0][la_r] = a4.x; As[la_k + 1][la_r] = a4.y;
                As[la_k + 2][la_r] = a4.z; As[la_k + 3][la_r] = a4.w;
                float4 b4 = *(const float4*)&Minv[(k0 + lb_k) * MOUT + j0 + lb_j];
                *(float4*)&Bs[lb_k][lb_j] = b4;
                __syncthreads();
                #pragma unroll
                for (int kk = 0; kk < 16; ++kk) {
                    float a_[4], b_[4];
                    #pragma unroll
                    for (int r = 0; r < 4; ++r) a_[r] = As[kk][(ty << 2) + r];
                    #pragma unroll
                    for (int c = 0; c < 4; ++c) b_[c] = Bs[kk][(tx << 2) + c];
                    #pragma unroll
                    for (int r = 0; r < 4; ++r)
                        #pragma unroll
                        for (int c = 0; c < 4; ++c)
                            acc[r][c] = fmaf(a_[r], b_[c], acc[r][c]);
                }
                __syncthreads();
            }
            #pragma unroll
            for (int r = 0; r < 4; ++r) {
                float4 o = make_float4(acc[r][0], acc[r][1], acc[r][2], acc[r][3]);
                *(float4*)&xk[(i0 + (ty << 2) + r) * MOUT + j0 + (tx << 2)] = o;
            }
        }
        grid.sync();

        // ---- phase B: per-row update (wave-uniform row)
        if (((volatile const int*)solved)[wrow] == 0) {
            float vn[16];
            float dx2 = 0.f, x2 = 0.f;
            const int rb = wrow * MOUT;
            #pragma unroll
            for (int c = 0; c < 16; ++c) {
                int j = rb + (c << 6) + lane;
                float kx = xk[j];
                float uu = u[j];
                float vv = v[j];
                float t  = kx + uu;
                float av = fabsf(t) - LAMBD;
                float vnew = av > 0.f ? copysignf(av, t) : 0.f;
                float un = uu + kx - vnew;
                float d  = vnew - vv;
                dx2 += d * d;
                x2  += vnew * vnew;
                v[j] = vnew;
                u[j] = un;
                beff[j] = adb[j] + vnew - un;
                vn[c] = vnew;
            }
            #pragma unroll
            for (int off = 32; off; off >>= 1) {
                dx2 += __shfl_xor(dx2, off);
                x2  += __shfl_xor(x2, off);
            }
            // dx/x < TOL  <=>  dx2 < TOL^2 * x2  (x2==0 -> false, matches NaN semantics)
            if (dx2 < TOLF * TOLF * x2) {
                #pragma unroll
                for (int c = 0; c < 16; ++c) enc[rb + (c << 6) + lane] = vn[c];
                if (lane == 0) {
                    ((volatile int*)solved)[wrow] = 1;
                    atomicAdd(cnt, 1);
                }
            }
        }
        grid.sync();
        if (((volatile const int*)cnt)[0] == BATCH) break;
    }
}

// ---------------------------------------------------------------------------
// dec = enc @ w   (1024x1024 * 1024x512 -> 1024x512)
// ---------------------------------------------------------------------------
__global__ __launch_bounds__(256) void gemm_dec(const float* __restrict__ enc,
                                                const float* __restrict__ w,
                                                float* __restrict__ dec) {
    __shared__ float As[16][72];
    __shared__ float Bs[16][72];
    const int tid = threadIdx.x;
    const int i0 = (blockIdx.x >> 3) * 64, j0 = (blockIdx.x & 7) * 64;
    const int tx = tid & 15, ty = tid >> 4;
    const int la_r = tid >> 2, la_k = (tid & 3) << 2;
    const int lb_k = tid >> 4, lb_j = (tid & 15) << 2;
    float acc[4][4] = {};
    for (int k0 = 0; k0 < MOUT; k0 += 16) {
        float4 a4 = *(const float4*)&enc[(i0 + la_r) * MOUT + k0 + la_k];
        As[la_k + 0][la_r] = a4.x; As[la_k + 1][la_r] = a4.y;
        As[la_k + 2][la_r] = a4.z; As[la_k + 3][la_r] = a4.w;
        float4 b4 = *(const float4*)&w[(k0 + lb_k) * NIN + j0 + lb_j];
        *(float4*)&Bs[lb_k][lb_j] = b4;
        __syncthreads();
        #pragma unroll
        for (int kk = 0; kk < 16; ++kk) {
            float a_[4], b_[4];
            #pragma unroll
            for (int r = 0; r < 4; ++r) a_[r] = As[kk][(ty << 2) + r];
            #pragma unroll
            for (int c = 0; c < 4; ++c) b_[c] = Bs[kk][(tx << 2) + c];
            #pragma unroll
            for (int r = 0; r < 4; ++r)
                #pragma unroll
                for (int c = 0; c < 4; ++c)
                    acc[r][c] = fmaf(a_[r], b_[c], acc[r][c]);
        }
        __syncthreads();
    }
    #pragma unroll
    for (int r = 0; r < 4; ++r) {
        float4 o = make_float4(acc[r][0], acc[r][1], acc[r][2], acc[r][3]);
        *(float4*)&dec[(i0 + (ty << 2) + r) * NIN + j0 + (tx << 2)] = o;
    }
}

// ---------------------------------------------------------------------------
extern "C" void kernel_launch(void* const* d_in, const int* in_sizes, int n_in,
                              void* d_out, int out_size, void* d_ws, size_t ws_size,
                              hipStream_t stream) {
    const float* x    = (const float*)d_in[0];
    const float* w    = (const float*)d_in[1];
    const float* Minv = (const float*)d_in[2];

    float* enc = (float*)d_out;          // encoded: 1024*1024
    float* dec = enc + MM;               // decoded: 1024*512

    float* ws   = (float*)d_ws;
    float* adb  = ws;                    // 1M
    float* beff = ws + (size_t)MM;       // 1M
    float* v    = ws + 2 * (size_t)MM;   // 1M
    float* u    = ws + 3 * (size_t)MM;   // 1M
    float* xk   = ws + 4 * (size_t)MM;   // 1M
    int* solved = (int*)(ws + 5 * (size_t)MM);  // 1024 flags + 1 counter
    int* cnt    = solved + BATCH;

    zero_init<<<(MM + 255) / 256, 256, 0, stream>>>(v, u, enc, solved);
    gemm_adb<<<256, 256, 0, stream>>>(x, w, adb, beff);

    void* args[] = {(void*)&adb, (void*)&beff, (void*)&v, (void*)&u, (void*)&xk,
                    (void*)&Minv, (void*)&enc, (void*)&solved, (void*)&cnt};
    hipLaunchCooperativeKernel((void*)admm_kernel, dim3(256), dim3(256), args, 0,
                               stream);

    gemm_dec<<<128, 256, 0, stream>>>(enc, w, dec);
}